// Round 10
// baseline (249.324 us; speedup 1.0000x reference)
//
#include <hip/hip_runtime.h>

typedef unsigned short u16;
typedef __attribute__((ext_vector_type(8))) short short8;
typedef __attribute__((ext_vector_type(4))) float floatx4;

#define N_TOK 2048
#define DIM   2048
#define NH    32
#define NKVH  4
#define HD    64
#define KVD   256

__device__ __forceinline__ float bf2f(u16 u) {
  union { unsigned i; float f; } c; c.i = ((unsigned)u) << 16; return c.f;
}
__device__ __forceinline__ u16 f2bf(float f) {
  union { float f; unsigned i; } c; c.f = f;
  unsigned x = c.i;
  return (u16)((x + 0x7fffu + ((x >> 16) & 1u)) >> 16);
}

// async global->LDS, 16B per lane (dest = wave-uniform base + lane*16)
__device__ __forceinline__ void gload16(const u16* g, u16* l) {
#if defined(__has_builtin) && __has_builtin(__builtin_amdgcn_global_load_lds)
  __builtin_amdgcn_global_load_lds(
      (const __attribute__((address_space(1))) void*)g,
      (__attribute__((address_space(3))) void*)l, 16, 0, 0);
#else
  *(short8*)l = *(const short8*)g;
#endif
}

// ---------------------------------------------------------------------------
// Fused fp32 -> bf16 conversion of x, Wq, Wk, Wv, Wo (float4 units).
// ---------------------------------------------------------------------------
#define C_X  1048576
#define C_WQ 2097152
#define C_WK 2228224
#define C_WV 2359296
#define C_WO 3407872
__global__ __launch_bounds__(256) void cvt_all(const float* __restrict__ x,
                                               const float* __restrict__ wq,
                                               const float* __restrict__ wk,
                                               const float* __restrict__ wv,
                                               const float* __restrict__ wo,
                                               u16* __restrict__ dst) {
  int i = blockIdx.x * 256 + threadIdx.x;
  const float* src; int off;
  if      (i < C_X)  { src = x;  off = 0; }
  else if (i < C_WQ) { src = wq; off = C_X; }
  else if (i < C_WK) { src = wk; off = C_WQ; }
  else if (i < C_WV) { src = wv; off = C_WK; }
  else               { src = wo; off = C_WV; }
  float4 v = ((const float4*)src)[i - off];
  ushort4 o;
  o.x = f2bf(v.x); o.y = f2bf(v.y); o.z = f2bf(v.z); o.w = f2bf(v.w);
  ((ushort4*)dst)[i] = o;
}

// ===========================================================================
// FRAG-PACKED LAYOUTS (u16 indices; lane = q*16 + r):
//  Qp: [(h*64 + sq)*4 + ii*2 + c]*512 + lane*8 + j
//      = Q_rope[token = sq*32 + 16*ii + r][dim = h*64 + 32c + 8q + j]
//  Kp: [(kvh*32 + kt)*8 + t*2 + c]*512 + lane*8 + j
//      = K_rope[token = kt*64 + 16t + r][dim = kvh*64 + 32c + 8q + j]
//  Vp: [(kvh*32 + kt)*8 + s*4 + t]*512 + lane*8 + j
//      = V[token = kt*64 + 32s + 8q + j][dim = kvh*64 + 16t + r]
// One fragment = contiguous 1KB = one gload16 wave instruction.
// ===========================================================================

// ---------------------------------------------------------------------------
// Fused QKV projection GEMM, 128x128 tiles, BK=32, RoPE fused, frag-packed.
// Grid 320: tm = bid&15, tn = bid>>4 (0..19): 0..15 Q; 16..17 K; 18..19 V.
// ---------------------------------------------------------------------------
__global__ __launch_bounds__(256) void gemm_qkv(const u16* __restrict__ A,
                                                const u16* __restrict__ Wq,
                                                const u16* __restrict__ Wk,
                                                const u16* __restrict__ Wv,
                                                const float* __restrict__ cs,
                                                const float* __restrict__ sn,
                                                u16* __restrict__ Qp,
                                                u16* __restrict__ Kp,
                                                u16* __restrict__ Vp) {
  __shared__ __align__(16) u16 As[128 * 32];
  __shared__ __align__(16) u16 Bs[128 * 32];
  const int tid  = threadIdx.x;
  const int lane = tid & 63;
  const int w    = tid >> 6;
  const int r    = lane & 15, q = lane >> 4;
  const int tm = blockIdx.x & 15;
  const int tn = blockIdx.x >> 4;   // 0..19
  const int wm = w & 1, wn = w >> 1;
  const int K = DIM;

  const u16* W; int wrow0;
  if (tn < 16)      { W = Wq; wrow0 = tn * 128; }
  else if (tn < 18) { W = Wk; wrow0 = (tn - 16) * 128; }
  else              { W = Wv; wrow0 = (tn - 18) * 128; }

  const int srow = w * 16 + (lane >> 2);
  const int scol = (lane & 3) * 8;
  const u16* ga = A + (size_t)(tm * 128 + srow) * K + scol;
  const u16* gb = W + (size_t)(wrow0 + srow) * K + scol;
  u16* lA = &As[w * 512 + lane * 8];
  u16* lB = &Bs[w * 512 + lane * 8];

  floatx4 acc[4][4];
#pragma unroll
  for (int a = 0; a < 4; ++a)
#pragma unroll
    for (int b = 0; b < 4; ++b) acc[a][b] = (floatx4){0.f, 0.f, 0.f, 0.f};

  for (int k0 = 0; k0 < K; k0 += 32) {
    __syncthreads();
    gload16(ga + k0, lA);
    gload16(ga + k0 + (size_t)64 * K, lA + 2048);
    gload16(gb + k0, lB);
    gload16(gb + k0 + (size_t)64 * K, lB + 2048);
    __syncthreads();

    short8 af[4], bf[4];
#pragma unroll
    for (int mi = 0; mi < 4; ++mi)
      af[mi] = *(const short8*)&As[(wm * 64 + mi * 16 + r) * 32 + q * 8];
#pragma unroll
    for (int nj = 0; nj < 4; ++nj)
      bf[nj] = *(const short8*)&Bs[(wn * 64 + nj * 16 + r) * 32 + q * 8];
#pragma unroll
    for (int mi = 0; mi < 4; ++mi)
#pragma unroll
      for (int nj = 0; nj < 4; ++nj)
        acc[mi][nj] = __builtin_amdgcn_mfma_f32_16x16x32_bf16(af[mi], bf[nj], acc[mi][nj], 0, 0, 0);
  }

  if (tn < 18) {
    // Q or K with fused RoPE, frag-packed out.
    const int head = (tn < 16) ? (tn * 2 + wn) : ((tn - 16) * 2 + wn);
#pragma unroll
    for (int mi = 0; mi < 4; ++mi)
#pragma unroll
      for (int g = 0; g < 4; ++g) {
        int row = tm * 128 + wm * 64 + mi * 16 + 4 * q + g;   // token
        const float* crow  = cs + (size_t)row * 64;
        const float* srow2 = sn + (size_t)row * 64;
#pragma unroll
        for (int nj = 0; nj < 2; ++nj) {
          int d = nj * 16 + r;               // head-dim 0..31 (pairs with d+32)
          float x0 = acc[mi][nj][g];
          float x1 = acc[mi][nj + 2][g];
          float o0 = x0 * crow[d]      - x1 * srow2[d];
          float o1 = x1 * crow[d + 32] + x0 * srow2[d + 32];
          int qq = d >> 3, j = d & 7;
          int lslot = (qq * 16 + (row & 15)) * 8 + j;
          if (tn < 16) {
            int sq = row >> 5, ii = (row >> 4) & 1;
            size_t base = ((size_t)(head * 64 + sq) * 4 + ii * 2) * 512 + lslot;
            Qp[base]       = f2bf(o0);       // c=0
            Qp[base + 512] = f2bf(o1);       // c=1
          } else {
            int kt = row >> 6, t = (row >> 4) & 3;
            size_t base = ((size_t)(head * 32 + kt) * 8 + t * 2) * 512 + lslot;
            Kp[base]       = f2bf(o0);
            Kp[base + 512] = f2bf(o1);
          }
        }
      }
  } else {
    // V frag-packed: uint2 = 4 consecutive tokens
#pragma unroll
    for (int mi = 0; mi < 4; ++mi)
#pragma unroll
      for (int nj = 0; nj < 4; ++nj) {
        int col  = (tn - 18) * 128 + wn * 64 + nj * 16 + r;   // dim 0..255
        int kvh  = col >> 6;
        int t    = (col & 63) >> 4;
        int rr   = col & 15;
        int row0 = tm * 128 + wm * 64 + mi * 16 + 4 * q;      // token
        int kt   = row0 >> 6;
        int wk   = row0 & 63;
        int s    = wk >> 5;
        int qq   = (wk & 31) >> 3;
        int j0   = wk & 7;                 // 0 or 4
        uint2 pk;
        pk.x = (unsigned)f2bf(acc[mi][nj][0]) | ((unsigned)f2bf(acc[mi][nj][1]) << 16);
        pk.y = (unsigned)f2bf(acc[mi][nj][2]) | ((unsigned)f2bf(acc[mi][nj][3]) << 16);
        size_t idx = ((size_t)(kvh * 32 + kt) * 8 + s * 4 + t) * 512 + (qq * 16 + rr) * 8 + j0;
        *(uint2*)(Vp + idx) = pk;
      }
  }
}

// ---------------------------------------------------------------------------
// Output GEMM, 128x128 tiles, split-K x2 (blockIdx.y = z, K-half 1024),
// bf16 partials. Grid (256, 2): tn = bid&15, tm = bid>>4.
// ---------------------------------------------------------------------------
__global__ __launch_bounds__(256) void gemm_out(const u16* __restrict__ A,
                                                const u16* __restrict__ W,
                                                u16* __restrict__ Pb) {
  __shared__ __align__(16) u16 As[128 * 32];
  __shared__ __align__(16) u16 Bs[128 * 32];
  const int tid  = threadIdx.x;
  const int lane = tid & 63;
  const int w    = tid >> 6;
  const int r    = lane & 15, q = lane >> 4;
  const int tn = blockIdx.x & 15;
  const int tm = blockIdx.x >> 4;
  const int z  = blockIdx.y;
  const int wm = w & 1, wn = w >> 1;
  const int K = DIM;

  const int srow = w * 16 + (lane >> 2);
  const int scol = (lane & 3) * 8;
  const u16* ga = A + (size_t)(tm * 128 + srow) * K + scol;
  const u16* gb = W + (size_t)(tn * 128 + srow) * K + scol;
  u16* lA = &As[w * 512 + lane * 8];
  u16* lB = &Bs[w * 512 + lane * 8];

  floatx4 acc[4][4];
#pragma unroll
  for (int a = 0; a < 4; ++a)
#pragma unroll
    for (int b = 0; b < 4; ++b) acc[a][b] = (floatx4){0.f, 0.f, 0.f, 0.f};

  const int kbeg = z * 1024, kend = kbeg + 1024;
  for (int k0 = kbeg; k0 < kend; k0 += 32) {
    __syncthreads();
    gload16(ga + k0, lA);
    gload16(ga + k0 + (size_t)64 * K, lA + 2048);
    gload16(gb + k0, lB);
    gload16(gb + k0 + (size_t)64 * K, lB + 2048);
    __syncthreads();

    short8 af[4], bf[4];
#pragma unroll
    for (int mi = 0; mi < 4; ++mi)
      af[mi] = *(const short8*)&As[(wm * 64 + mi * 16 + r) * 32 + q * 8];
#pragma unroll
    for (int nj = 0; nj < 4; ++nj)
      bf[nj] = *(const short8*)&Bs[(wn * 64 + nj * 16 + r) * 32 + q * 8];
#pragma unroll
    for (int mi = 0; mi < 4; ++mi)
#pragma unroll
      for (int nj = 0; nj < 4; ++nj)
        acc[mi][nj] = __builtin_amdgcn_mfma_f32_16x16x32_bf16(af[mi], bf[nj], acc[mi][nj], 0, 0, 0);
  }

  u16* P = Pb + (size_t)z * N_TOK * DIM;
#pragma unroll
  for (int mi = 0; mi < 4; ++mi)
#pragma unroll
    for (int g = 0; g < 4; ++g) {
      int row = tm * 128 + wm * 64 + mi * 16 + 4 * q + g;
#pragma unroll
      for (int nj = 0; nj < 4; ++nj)
        P[(size_t)row * DIM + tn * 128 + wn * 64 + nj * 16 + r] = f2bf(acc[mi][nj][g]);
    }
}

// ---------------------------------------------------------------------------
// Combine split-K partials: d_out = fp32(P0) + fp32(P1). 8 elems/thread.
// ---------------------------------------------------------------------------
__global__ __launch_bounds__(256) void combine_out(const u16* __restrict__ Pb,
                                                   float* __restrict__ out) {
  int idx = blockIdx.x * 256 + threadIdx.x;       // 8-elem chunk
  const short8 a = *(const short8*)(Pb + (size_t)idx * 8);
  const short8 b = *(const short8*)(Pb + (size_t)N_TOK * DIM + (size_t)idx * 8);
  float4 o0, o1;
  o0.x = bf2f((u16)a[0]) + bf2f((u16)b[0]);
  o0.y = bf2f((u16)a[1]) + bf2f((u16)b[1]);
  o0.z = bf2f((u16)a[2]) + bf2f((u16)b[2]);
  o0.w = bf2f((u16)a[3]) + bf2f((u16)b[3]);
  o1.x = bf2f((u16)a[4]) + bf2f((u16)b[4]);
  o1.y = bf2f((u16)a[5]) + bf2f((u16)b[5]);
  o1.z = bf2f((u16)a[6]) + bf2f((u16)b[6]);
  o1.w = bf2f((u16)a[7]) + bf2f((u16)b[7]);
  ((float4*)out)[idx * 2]     = o0;
  ((float4*)out)[idx * 2 + 1] = o1;
}

// ---------------------------------------------------------------------------
// MFMA flash attention, m97-style: 4 waves share a double-buffered K/V LDS
// tile staged via global_load_lds from frag-packed Kp/Vp (wave-uniform base +
// lane*16 -> legal). One barrier per K-tile; stage(kt+1) issues before
// compute(kt). Block = (qt, h); wave w owns q-rows qt*128 + w*32 .. +31.
// ---------------------------------------------------------------------------
__global__ __launch_bounds__(256) void attn_mfma(const u16* __restrict__ Qp,
                                                 const u16* __restrict__ Kp,
                                                 const u16* __restrict__ Vp,
                                                 u16* __restrict__ Yb) {
  __shared__ __align__(16) u16 Kbuf[2][8 * 512];
  __shared__ __align__(16) u16 Vbuf[2][8 * 512];
  __shared__ __align__(16) u16 Pl[4][32][72];
  const int tid  = threadIdx.x;
  const int lane = tid & 63;
  const int w    = tid >> 6;
  const int r    = lane & 15;
  const int q    = lane >> 4;
  const int qt   = 15 - blockIdx.x;          // heavy blocks first
  const int h    = blockIdx.y;
  const int kvh  = h >> 3;
  const int baseq = qt * 128 + w * 32;
  const int ktmax_blk = 2 * qt + 1;          // block-wide loop bound
  const int ktmax_w   = (baseq + 31) >> 6;   // this wave's last useful tile

  const u16* Kg = Kp + (size_t)(kvh * 32) * 4096;   // per-kt chunk = 4096 u16
  const u16* Vg = Vp + (size_t)(kvh * 32) * 4096;

  // Q frags (frag-packed, 1KB wave reads)
  short8 qf[2][2];
#pragma unroll
  for (int i = 0; i < 2; ++i)
#pragma unroll
    for (int c = 0; c < 2; ++c)
      qf[i][c] = *(const short8*)(Qp +
          ((size_t)(h * 64 + qt * 4 + w) * 4 + i * 2 + c) * 512 + lane * 8);

  floatx4 O[2][4];
  float lsum[2];
#pragma unroll
  for (int i = 0; i < 2; ++i) {
    lsum[i] = 0.f;
#pragma unroll
    for (int t = 0; t < 4; ++t) O[i][t] = (floatx4){0.f, 0.f, 0.f, 0.f};
  }

  // staging: waves 0,1 -> K frags 0..7; waves 2,3 -> V frags 0..7
  auto stage = [&](int kt, int buf) {
    const u16* src = ((w < 2) ? Kg : Vg) + (size_t)kt * 4096;
    u16* dst = (w < 2) ? &Kbuf[buf][0] : &Vbuf[buf][0];
    const int f0 = (w & 1) * 4;
#pragma unroll
    for (int j = 0; j < 4; ++j)
      gload16(src + (f0 + j) * 512 + lane * 8, dst + (f0 + j) * 512 + lane * 8);
  };

  stage(0, 0);
  __syncthreads();                            // buf0 ready (vmcnt drained)

  for (int kt = 0; kt <= ktmax_blk; ++kt) {
    const int buf = kt & 1;
    if (kt < ktmax_blk) stage(kt + 1, buf ^ 1);   // async prefetch

    if (kt <= ktmax_w) {
      // ---- S^T = K Q^T (K frags from LDS) ----
      floatx4 ST[2][4];
#pragma unroll
      for (int i = 0; i < 2; ++i)
#pragma unroll
        for (int t = 0; t < 4; ++t) ST[i][t] = (floatx4){0.f, 0.f, 0.f, 0.f};
#pragma unroll
      for (int t = 0; t < 4; ++t) {
        short8 kf0 = *(const short8*)&Kbuf[buf][(t * 2 + 0) * 512 + lane * 8];
        short8 kf1 = *(const short8*)&Kbuf[buf][(t * 2 + 1) * 512 + lane * 8];
#pragma unroll
        for (int i = 0; i < 2; ++i) {
          ST[i][t] = __builtin_amdgcn_mfma_f32_16x16x32_bf16(kf0, qf[i][0], ST[i][t], 0, 0, 0);
          ST[i][t] = __builtin_amdgcn_mfma_f32_16x16x32_bf16(kf1, qf[i][1], ST[i][t], 0, 0, 0);
        }
      }

      // ---- causal mask (only this wave's last tile can clip) ----
      if (kt == ktmax_w) {
#pragma unroll
        for (int i = 0; i < 2; ++i) {
          int qrow = baseq + 16 * i + r;
#pragma unroll
          for (int t = 0; t < 4; ++t) {
            int key = kt * 64 + 16 * t + 4 * q;
#pragma unroll
            for (int g = 0; g < 4; ++g)
              if (key + g > qrow) ST[i][t][g] = -1e30f;
          }
        }
      }

      // ---- p = exp(scale*s); per-lane row-sums; packed P -> LDS ----
#pragma unroll
      for (int i = 0; i < 2; ++i)
#pragma unroll
        for (int t = 0; t < 4; ++t) {
          float p0 = __expf(0.125f * ST[i][t][0]);
          float p1 = __expf(0.125f * ST[i][t][1]);
          float p2 = __expf(0.125f * ST[i][t][2]);
          float p3 = __expf(0.125f * ST[i][t][3]);
          lsum[i] += (p0 + p1) + (p2 + p3);
          uint2 pk;
          pk.x = (unsigned)f2bf(p0) | ((unsigned)f2bf(p1) << 16);
          pk.y = (unsigned)f2bf(p2) | ((unsigned)f2bf(p3) << 16);
          *(uint2*)&Pl[w][16 * i + r][16 * t + 4 * q] = pk;
        }

      // ---- O += P V (both operands from LDS) ----
#pragma unroll
      for (int s = 0; s < 2; ++s) {
        short8 vb[4];
#pragma unroll
        for (int t = 0; t < 4; ++t)
          vb[t] = *(const short8*)&Vbuf[buf][(s * 4 + t) * 512 + lane * 8];
#pragma unroll
        for (int i = 0; i < 2; ++i) {
          short8 pa = *(const short8*)&Pl[w][16 * i + r][32 * s + 8 * q];
#pragma unroll
          for (int t = 0; t < 4; ++t)
            O[i][t] = __builtin_amdgcn_mfma_f32_16x16x32_bf16(pa, vb[t], O[i][t], 0, 0, 0);
        }
      }
    }

    __syncthreads();   // all waves done with buf; stage(kt+1) drained
  }

  // ---- reduce row-sums over q-groups, normalize, store ----
#pragma unroll
  for (int i = 0; i < 2; ++i) {
    lsum[i] += __shfl_xor(lsum[i], 16);
    lsum[i] += __shfl_xor(lsum[i], 32);   // lane(q,r) holds sum for row r
  }

#pragma unroll
  for (int i = 0; i < 2; ++i) {
    float inv[4];
#pragma unroll
    for (int g = 0; g < 4; ++g)
      inv[g] = 1.f / __shfl(lsum[i], 4 * q + g);
#pragma unroll
    for (int g = 0; g < 4; ++g) {
      u16* yp = Yb + (size_t)(baseq + 16 * i + 4 * q + g) * DIM + h * 64 + r;
      yp[0]  = f2bf(O[i][0][g] * inv[g]);
      yp[16] = f2bf(O[i][1][g] * inv[g]);
      yp[32] = f2bf(O[i][2][g] * inv[g]);
      yp[48] = f2bf(O[i][3][g] * inv[g]);
    }
  }
}

// ---------------------------------------------------------------------------
extern "C" void kernel_launch(void* const* d_in, const int* in_sizes, int n_in,
                              void* d_out, int out_size, void* d_ws, size_t ws_size,
                              hipStream_t stream) {
  const float* x  = (const float*)d_in[0];
  const float* Wq = (const float*)d_in[1];
  const float* Wk = (const float*)d_in[2];
  const float* Wv = (const float*)d_in[3];
  const float* Wo = (const float*)d_in[4];
  const float* cs = (const float*)d_in[5];
  const float* sn = (const float*)d_in[6];

  u16* ws  = (u16*)d_ws;
  u16* xb  = ws;                            // order must match cvt_all segments
  u16* Wqb = xb  + (size_t)N_TOK * DIM;
  u16* Wkb = Wqb + (size_t)DIM * DIM;
  u16* Wvb = Wkb + (size_t)KVD * DIM;
  u16* Wob = Wvb + (size_t)KVD * DIM;
  u16* Qp  = Wob + (size_t)DIM * DIM;       // frag-packed Q (8MB)
  u16* Kp  = Qp  + (size_t)N_TOK * DIM;     // frag-packed K (1MB)
  u16* Vp  = Kp  + (size_t)N_TOK * KVD;     // frag-packed V (1MB)
  u16* Yb  = Vp  + (size_t)N_TOK * KVD;

  // out-proj split-K partials (bf16, 2 x 8.4MB) alias dead xb/Wqb/Wkb region
  u16* Pb  = xb;

  // fp32 -> bf16 (x + 4 weights); cos/sin consumed fp32 by gemm_qkv
  cvt_all<<<dim3(13312), 256, 0, stream>>>(x, Wq, Wk, Wv, Wo, ws);

  // Fused QKV projection + RoPE, frag-packed outputs (128x128 tiles)
  gemm_qkv<<<dim3(320), 256, 0, stream>>>(xb, Wqb, Wkb, Wvb, cs, sn, Qp, Kp, Vp);

  // m97-style attention: (16 qt) x (32 heads), 4 waves + LDS dbuf staging
  attn_mfma<<<dim3(16, 32), 256, 0, stream>>>(Qp, Kp, Vp, Yb);

  // Output projection: 128x128, split-K x2 -> bf16 partials
  gemm_out<<<dim3(256, 2), 256, 0, stream>>>(Yb, Wob, Pb);

  // Combine partials -> fp32 d_out
  combine_out<<<dim3(2048), 256, 0, stream>>>(Pb, (float*)d_out);
}